// Round 6
// baseline (753.338 us; speedup 1.0000x reference)
//
#include <hip/hip_runtime.h>
#include <hip/hip_bf16.h>
#include <stdint.h>

#define M_DIM 8192
#define N_DIM 4096
#define K_DIM 4096
#define BM 256
#define BN 256
#define BK 64
#define NTL 64

typedef __attribute__((ext_vector_type(8))) short short8;
typedef __attribute__((ext_vector_type(4))) float f32x4;
typedef unsigned short ushort_t;

#define SBAR()  asm volatile("s_barrier" ::: "memory")
#define LGKM(n) asm volatile("s_waitcnt lgkmcnt(" #n ")" ::: "memory")
#define VM(n)   asm volatile("s_waitcnt vmcnt(" #n ")" ::: "memory")
#define SCHEDB() __builtin_amdgcn_sched_barrier(0)

// ---------- fp32 -> bf16 (RNE) conversion ----------
__device__ __forceinline__ ushort_t f2bf(float f) {
    uint32_t u = __float_as_uint(f);
    uint32_t r = (u + 0x7FFFu + ((u >> 16) & 1u)) >> 16;
    return (ushort_t)r;
}

__global__ void cvt_f32_bf16(const float4* __restrict__ in, ushort* __restrict__ out4, int n4) {
    int i = blockIdx.x * blockDim.x + threadIdx.x;
    if (i < n4) {
        float4 v = in[i];
        ushort_t a = f2bf(v.x), b = f2bf(v.y), c = f2bf(v.z), d = f2bf(v.w);
        uint32_t lo = (uint32_t)a | ((uint32_t)b << 16);
        uint32_t hi = (uint32_t)c | ((uint32_t)d << 16);
        uint2* o = reinterpret_cast<uint2*>(out4);
        o[i] = make_uint2(lo, hi);
    }
}

__device__ __forceinline__ void gload_lds16(const ushort_t* g, void* l) {
    __builtin_amdgcn_global_load_lds(
        (const __attribute__((address_space(1))) unsigned int*)g,
        (__attribute__((address_space(3))) unsigned int*)l,
        16, 0, 0);
}

// ---------- fused GEMM (x @ W^T) + GroupNorm + bias + clamp ----------
// 256x256 tile, BK=64, 512 thr (8 waves 2Mx4N), 2x64KB dbuf.
// Intra-wave pipelined: each quadrant's ds_reads issue UNDER the previous
// quadrant's MFMA cluster (counted lgkm). ONE barrier per tile; region
// invariant: between SBAR(T) and SBAR(T+1) block writes only buf T&1
// (tile T+2 stages) and reads only buf ~T&1 (tile T+1 fragments).
__global__ __launch_bounds__(512, 2)
void gemm_gn_kernel(const ushort_t* __restrict__ xb,   // [M][K] bf16
                    const ushort_t* __restrict__ wb,   // [N][K] bf16
                    const float*   __restrict__ bias,  // [N]
                    float*         __restrict__ out)   // [M][N]
{
    __shared__ char pool[131072];   // 2 buf x (A 32K [256r x 128B] + B 32K)

    const int tid = threadIdx.x;
    const int w   = tid >> 6;          // wave 0..7
    const int l   = tid & 63;
    const int wr  = w >> 2;            // 0..1 (M)
    const int wc  = w & 3;             // 0..3 (N)
    const int l15 = l & 15;
    const int l4  = l >> 4;

    // bijective XCD swizzle (512 blocks = 8*64)
    const int TN = N_DIM / BN;         // 16
    int bid = blockIdx.x;
    bid = (bid & 7) * 64 + (bid >> 3);
    const int brow = (bid / TN) * BM;
    const int bcol = (bid % TN) * BN;

    // ---- staging: half-tile = 128 rows x 128B = 16KB = 512thr x 2 gloads x 16B
    // LDS dest linear; global SOURCE pre-swizzled: slot ^= row&7 (rule #21)
    const int srow8 = tid >> 3;                      // 0..63
    const int sslot = (tid & 7) ^ (srow8 & 7);
    const ushort_t* gA = xb + (size_t)(brow + srow8) * K_DIM + sslot * 8;
    const ushort_t* gB = wb + (size_t)(bcol + srow8) * K_DIM + sslot * 8;
    const size_t ROW64 = (size_t)64 * K_DIM;
    const int w1024 = w * 1024;

    auto STAGE_A = [&](int buf, int half, int kt) {
        const ushort_t* s = gA + (size_t)half * 128 * K_DIM + (size_t)kt * 64;
        char* d = pool + buf * 65536 + half * 16384 + w1024;
        gload_lds16(s,         d);
        gload_lds16(s + ROW64, d + 8192);
    };
    auto STAGE_B = [&](int buf, int half, int kt) {
        const ushort_t* s = gB + (size_t)half * 128 * K_DIM + (size_t)kt * 64;
        char* d = pool + buf * 65536 + 32768 + half * 16384 + w1024;
        gload_lds16(s,         d);
        gload_lds16(s + ROW64, d + 8192);
    };

    // fragment read addressing; row&7 == l15&7 matches stage-side swizzle
    const int swz = (l15 & 7) << 4;
    const int x0  = (l4 * 16) ^ swz;
    const int x1  = (64 + l4 * 16) ^ swz;

    // m-frag mi -> tile row mi*32 + wr*16 + l15  (mi 0-3 = A-lo, 4-7 = A-hi)
    // n-frag ni -> tile col ni*64 + wc*16 + l15  (ni 0-1 = B-lo, 2-3 = B-hi)
    short8 afL[8], afH[8], bfL[4], bfH[4];

    auto RD_A = [&](short8* dst, const char* Ab, int mi0) {
#pragma unroll
        for (int m = 0; m < 4; ++m) {
            const char* p = Ab + ((mi0 + m) * 32 + wr * 16 + l15) * 128;
            dst[m * 2]     = *(const short8*)(p + x0);
            dst[m * 2 + 1] = *(const short8*)(p + x1);
        }
    };
    auto RD_B = [&](short8* dst, const char* Bb, int ni0) {
#pragma unroll
        for (int n = 0; n < 2; ++n) {
            const char* p = Bb + ((ni0 + n) * 64 + wc * 16 + l15) * 128;
            dst[n * 2]     = *(const short8*)(p + x0);
            dst[n * 2 + 1] = *(const short8*)(p + x1);
        }
    };

    f32x4 acc[8][4];
#pragma unroll
    for (int i = 0; i < 8; ++i)
#pragma unroll
        for (int j = 0; j < 4; ++j) acc[i][j] = (f32x4){0.f, 0.f, 0.f, 0.f};

    auto MM = [&](short8* A, short8* B, int m0, int n0) {
        __builtin_amdgcn_s_setprio(1);
#pragma unroll
        for (int k = 0; k < 2; ++k)
#pragma unroll
            for (int m = 0; m < 4; ++m)
#pragma unroll
                for (int n = 0; n < 2; ++n)
                    acc[m0 + m][n0 + n] = __builtin_amdgcn_mfma_f32_16x16x32_bf16(
                        A[m * 2 + k], B[n * 2 + k], acc[m0 + m][n0 + n], 0, 0, 0);
        __builtin_amdgcn_s_setprio(0);
    };

    // ---- prologue: stage tile0 -> buf0 (8 gld), tile1 -> buf1 (8 gld)
    STAGE_A(0, 0, 0); STAGE_A(0, 1, 0); STAGE_B(0, 0, 0); STAGE_B(0, 1, 0);
    STAGE_A(1, 0, 1); STAGE_A(1, 1, 1); STAGE_B(1, 0, 1); STAGE_B(1, 1, 1);
    VM(8);                         // tile0 landed; tile1's 8 stay in flight
    SBAR();
    RD_A(afL, pool, 0);            // afL(T0): 8 ds
    RD_B(bfL, pool + 32768, 0);    // bfL(T0): 4 ds
    SCHEDB();

#pragma unroll 2
    for (int T = 0; T < NTL; ++T) {
        const int c = T & 1;
        const char* Cur = pool + c * 65536;          // tile T fragments
        const char* Nxt = pool + (c ^ 1) * 65536;    // tile T+1 fragments

        // Q1 (mLo x nLo): issue bfH(T) reads, wait afL/bfL, MFMA
        RD_B(bfH, Cur + 32768, 2);                   // 4 ds, under nothing (tail cover)
        SCHEDB();
        LGKM(4);                                     // afL(T), bfL(T) done; bfH in flight
        SCHEDB();
        MM(afL, bfL, 0, 0);

        // Q2 (mLo x nHi): issue afH(T) reads under Q1's MFMA drain
        RD_A(afH, Cur, 4);                           // 8 ds
        SCHEDB();
        LGKM(8);                                     // bfH done; afH in flight
        SCHEDB();
        MM(afL, bfH, 0, 2);

        // Q3 (mHi x nHi): drain, certify, barrier; stage A(T+2); read afL(T+1)
        LGKM(0);                                     // afH done (all buf-c reads retired)
        VM(0);                                       // all tile T+1 stages landed (issued T-1, ~3 clusters cover)
        SCHEDB();
        SBAR();                                      // region flip: now write c, read c^1
        if (T + 2 < NTL) { STAGE_A(c, 0, T + 2); STAGE_A(c, 1, T + 2); }
        if (T + 1 < NTL) RD_A(afL, Nxt, 0);          // 8 ds (afL dead since Q2)
        SCHEDB();
        MM(afH, bfH, 4, 2);

        // Q4 (mHi x nLo): stage B(T+2); MFMA; then refill bfL (WAR: after MM)
        if (T + 2 < NTL) { STAGE_B(c, 0, T + 2); STAGE_B(c, 1, T + 2); }
        SCHEDB();
        MM(afH, bfL, 4, 0);
        if (T + 1 < NTL) RD_B(bfL, Nxt + 32768, 0);  // 4 ds
        SCHEDB();
    }

    __syncthreads();

    // ---------- fused GroupNorm epilogue ----------
    // acc[mi][n][r]: row = mi*32+wr*16+l4*4+r, col = n*64+wc*16+l15
    // group 0 = cols 0-127 (n=0,1), group 1 = cols 128-255 (n=2,3)
    float* redS  = (float*)pool;            // [256][4wc][2g]
    float* redS2 = (float*)(pool + 8192);
#pragma unroll
    for (int mi = 0; mi < 8; ++mi)
#pragma unroll
        for (int r = 0; r < 4; ++r) {
            float gl  = acc[mi][0][r] + acc[mi][1][r];
            float gh  = acc[mi][2][r] + acc[mi][3][r];
            float gl2 = acc[mi][0][r] * acc[mi][0][r] + acc[mi][1][r] * acc[mi][1][r];
            float gh2 = acc[mi][2][r] * acc[mi][2][r] + acc[mi][3][r] * acc[mi][3][r];
#pragma unroll
            for (int m = 1; m < 16; m <<= 1) {
                gl  += __shfl_xor(gl,  m);
                gh  += __shfl_xor(gh,  m);
                gl2 += __shfl_xor(gl2, m);
                gh2 += __shfl_xor(gh2, m);
            }
            if (l15 == 0) {
                int R = mi * 32 + wr * 16 + l4 * 4 + r;
                redS [R * 8 + wc * 2]     = gl;
                redS [R * 8 + wc * 2 + 1] = gh;
                redS2[R * 8 + wc * 2]     = gl2;
                redS2[R * 8 + wc * 2 + 1] = gh2;
            }
        }
    __syncthreads();

    float bv[4];
#pragma unroll
    for (int ni = 0; ni < 4; ++ni)
        bv[ni] = bias[bcol + ni * 64 + wc * 16 + l15];

    const float inv_gs = 1.0f / 128.0f;
#pragma unroll
    for (int mi = 0; mi < 8; ++mi)
#pragma unroll
        for (int r = 0; r < 4; ++r) {
            int R = mi * 32 + wr * 16 + l4 * 4 + r;
            float S0 = redS [R * 8 + 0] + redS [R * 8 + 2] + redS [R * 8 + 4] + redS [R * 8 + 6];
            float S1 = redS [R * 8 + 1] + redS [R * 8 + 3] + redS [R * 8 + 5] + redS [R * 8 + 7];
            float T0 = redS2[R * 8 + 0] + redS2[R * 8 + 2] + redS2[R * 8 + 4] + redS2[R * 8 + 6];
            float T1 = redS2[R * 8 + 1] + redS2[R * 8 + 3] + redS2[R * 8 + 5] + redS2[R * 8 + 7];
            float mean0 = S0 * inv_gs, mean1 = S1 * inv_gs;
            float inv0 = rsqrtf(T0 * inv_gs - mean0 * mean0 + 1e-6f);
            float inv1 = rsqrtf(T1 * inv_gs - mean1 * mean1 + 1e-6f);
            size_t rowbase = (size_t)(brow + R) * N_DIM + bcol + wc * 16 + l15;
#pragma unroll
            for (int ni = 0; ni < 4; ++ni) {
                float mean = (ni < 2) ? mean0 : mean1;
                float inv  = (ni < 2) ? inv0  : inv1;
                float v = (acc[mi][ni][r] - mean) * inv + bv[ni];
                v = fminf(fmaxf(v, -2.0f), 2.0f);
                out[rowbase + ni * 64] = v;
            }
        }
}

extern "C" void kernel_launch(void* const* d_in, const int* in_sizes, int n_in,
                              void* d_out, int out_size, void* d_ws, size_t ws_size,
                              hipStream_t stream) {
    const float* x = (const float*)d_in[0];
    const float* W = (const float*)d_in[1];
    const float* b = (const float*)d_in[2];
    float* out = (float*)d_out;

    ushort_t* xb = (ushort_t*)d_ws;                       // 64 MB
    ushort_t* wb = xb + (size_t)M_DIM * K_DIM;            // +32 MB

    int n4x = M_DIM * K_DIM / 4;
    cvt_f32_bf16<<<(n4x + 255) / 256, 256, 0, stream>>>(
        (const float4*)x, xb, n4x);
    int n4w = N_DIM * K_DIM / 4;
    cvt_f32_bf16<<<(n4w + 255) / 256, 256, 0, stream>>>(
        (const float4*)W, wb, n4w);

    int grid = (M_DIM / BM) * (N_DIM / BN);               // 512 blocks
    gemm_gn_kernel<<<grid, 512, 0, stream>>>(xb, wb, b, out);
}

// Round 7
// 323.110 us; speedup vs baseline: 2.3315x; 2.3315x over previous
//
#include <hip/hip_runtime.h>
#include <hip/hip_bf16.h>
#include <stdint.h>

#define M_DIM 8192
#define N_DIM 4096
#define K_DIM 4096
#define BM 256
#define BN 256
#define BK 64
#define NTL 64

typedef __attribute__((ext_vector_type(8))) short short8;
typedef __attribute__((ext_vector_type(4))) float f32x4;
typedef unsigned short ushort_t;

// De-fenced sync (m201 style): barriers/lgkm are NOT compiler fences, so the
// scheduler may sink ds_reads/MFMAs across phases (read||MFMA overlap).
// Safety: ds_reads cannot cross any global_load_lds (LDS alias) -> confined
// within +-1 phase; every overwrite is >=2 phases from its region's reads.
#define SBAR()   __builtin_amdgcn_s_barrier()
#define LGKM(n)  asm volatile("s_waitcnt lgkmcnt(" #n ")")
#define VMF(n)   asm volatile("s_waitcnt vmcnt(" #n ")" ::: "memory")

// ---------- fp32 -> bf16 (RNE) conversion ----------
__device__ __forceinline__ ushort_t f2bf(float f) {
    uint32_t u = __float_as_uint(f);
    uint32_t r = (u + 0x7FFFu + ((u >> 16) & 1u)) >> 16;
    return (ushort_t)r;
}

__global__ void cvt_f32_bf16(const float4* __restrict__ in, ushort* __restrict__ out4, int n4) {
    int i = blockIdx.x * blockDim.x + threadIdx.x;
    if (i < n4) {
        float4 v = in[i];
        ushort_t a = f2bf(v.x), b = f2bf(v.y), c = f2bf(v.z), d = f2bf(v.w);
        uint32_t lo = (uint32_t)a | ((uint32_t)b << 16);
        uint32_t hi = (uint32_t)c | ((uint32_t)d << 16);
        uint2* o = reinterpret_cast<uint2*>(out4);
        o[i] = make_uint2(lo, hi);
    }
}

__device__ __forceinline__ void gload_lds16(const ushort_t* g, void* l) {
    __builtin_amdgcn_global_load_lds(
        (const __attribute__((address_space(1))) unsigned int*)g,
        (__attribute__((address_space(3))) unsigned int*)l,
        16, 0, 0);
}

// ---------- fused GEMM (x @ W^T) + GroupNorm + bias + clamp ----------
// m201 schedule: 256x256 tile, BK=64, 512 thr (8 waves 2Mx4N), 2x64KB dbuf,
// 4 phases/tile, stage stagger {Bhi(T+1),Alo(T+2),Ahi(T+2),Blo(T+2)},
// vmcnt(6) once per tile at P4 certifies ALL of tile T+1 before its reads.
__global__ __launch_bounds__(512, 2)
void gemm_gn_kernel(const ushort_t* __restrict__ xb,   // [M][K] bf16
                    const ushort_t* __restrict__ wb,   // [N][K] bf16
                    const float*   __restrict__ bias,  // [N]
                    float*         __restrict__ out)   // [M][N]
{
    __shared__ char pool[131072];   // 2 buf x (A 32K [256r x 128B] + B 32K)

    const int tid = threadIdx.x;
    const int w   = tid >> 6;          // wave 0..7
    const int l   = tid & 63;
    const int wr  = w >> 2;            // 0..1 (M)
    const int wc  = w & 3;             // 0..3 (N)
    const int l15 = l & 15;
    const int l4  = l >> 4;

    // bijective XCD swizzle (512 blocks = 8*64)
    const int TN = N_DIM / BN;         // 16
    int bid = blockIdx.x;
    bid = (bid & 7) * 64 + (bid >> 3);
    const int brow = (bid / TN) * BM;
    const int bcol = (bid % TN) * BN;

    // ---- staging: half-tile = 128 rows x 128B = 16KB = 512thr x 2 gloads x 16B
    // LDS dest linear; global SOURCE pre-swizzled: slot ^= row&7 (rule #21)
    const int srow8 = tid >> 3;                      // 0..63
    const int sslot = (tid & 7) ^ (srow8 & 7);
    const ushort_t* gA = xb + (size_t)(brow + srow8) * K_DIM + sslot * 8;
    const ushort_t* gB = wb + (size_t)(bcol + srow8) * K_DIM + sslot * 8;
    const size_t ROW64 = (size_t)64 * K_DIM;
    const int w1024 = w * 1024;

    auto STAGE_A = [&](int buf, int half, int kt) {
        const ushort_t* s = gA + (size_t)half * 128 * K_DIM + (size_t)kt * 64;
        char* d = pool + buf * 65536 + half * 16384 + w1024;
        gload_lds16(s,         d);
        gload_lds16(s + ROW64, d + 8192);
    };
    auto STAGE_B = [&](int buf, int half, int kt) {
        const ushort_t* s = gB + (size_t)half * 128 * K_DIM + (size_t)kt * 64;
        char* d = pool + buf * 65536 + 32768 + half * 16384 + w1024;
        gload_lds16(s,         d);
        gload_lds16(s + ROW64, d + 8192);
    };

    // fragment read addressing; row&7 == l15&7 matches stage-side swizzle
    const int swz = (l15 & 7) << 4;
    const int x0  = (l4 * 16) ^ swz;
    const int x1  = (64 + l4 * 16) ^ swz;

    // m-frag mi -> tile row mi*32 + wr*16 + l15  (mi 0-3 = A-lo, 4-7 = A-hi)
    // n-frag ni -> tile col ni*64 + wc*16 + l15  (ni 0-1 = B-lo, 2-3 = B-hi)
    short8 afL[8], afH[8], bfL[4], bfH[4];

    auto RD_A = [&](short8* dst, const char* Ab, int mi0) {
#pragma unroll
        for (int m = 0; m < 4; ++m) {
            const char* p = Ab + ((mi0 + m) * 32 + wr * 16 + l15) * 128;
            dst[m * 2]     = *(const short8*)(p + x0);
            dst[m * 2 + 1] = *(const short8*)(p + x1);
        }
    };
    auto RD_B = [&](short8* dst, const char* Bb, int ni0) {
#pragma unroll
        for (int n = 0; n < 2; ++n) {
            const char* p = Bb + ((ni0 + n) * 64 + wc * 16 + l15) * 128;
            dst[n * 2]     = *(const short8*)(p + x0);
            dst[n * 2 + 1] = *(const short8*)(p + x1);
        }
    };

    f32x4 acc[8][4];
#pragma unroll
    for (int i = 0; i < 8; ++i)
#pragma unroll
        for (int j = 0; j < 4; ++j) acc[i][j] = (f32x4){0.f, 0.f, 0.f, 0.f};

    auto MM = [&](short8* A, short8* B, int m0, int n0) {
        __builtin_amdgcn_s_setprio(1);
#pragma unroll
        for (int k = 0; k < 2; ++k)
#pragma unroll
            for (int m = 0; m < 4; ++m)
#pragma unroll
                for (int n = 0; n < 2; ++n)
                    acc[m0 + m][n0 + n] = __builtin_amdgcn_mfma_f32_16x16x32_bf16(
                        A[m * 2 + k], B[n * 2 + k], acc[m0 + m][n0 + n], 0, 0, 0);
        __builtin_amdgcn_s_setprio(0);
    };

    // ---- prologue: tile0 all 4 halves + tile1 {Alo,Ahi,Blo}; vmcnt(6) drains tile0
    STAGE_A(0, 0, 0); STAGE_A(0, 1, 0);
    STAGE_B(0, 0, 0); STAGE_B(0, 1, 0);
    STAGE_A(1, 0, 1); STAGE_A(1, 1, 1);
    STAGE_B(1, 0, 1);
    VMF(6);
    SBAR();

#pragma unroll 2
    for (int T = 0; T < NTL; ++T) {
        const int c = T & 1;
        const char* Ab = pool + c * 65536;
        const char* Bb = Ab + 32768;

        // P1: Q(mLo,nLo); reads afL(8)+bfL(4); stage B-hi(T+1)
        RD_A(afL, Ab, 0);
        RD_B(bfL, Bb, 0);
        if (T + 1 < NTL) STAGE_B(c ^ 1, 1, T + 1);
        LGKM(8);
        SBAR(); LGKM(0);
        MM(afL, bfL, 0, 0);
        SBAR();

        // P2: Q(mHi,nLo); reads afH(8); stage A-lo(T+2) (curr buf, safe after P1 bar)
        RD_A(afH, Ab, 4);
        if (T + 2 < NTL) STAGE_A(c, 0, T + 2);
        SBAR(); LGKM(0);
        MM(afH, bfL, 4, 0);
        SBAR();

        // P3: Q(mHi,nHi); reads bfH(4); stage A-hi(T+2)
        RD_B(bfH, Bb, 2);
        if (T + 2 < NTL) STAGE_A(c, 1, T + 2);
        SBAR(); LGKM(0);
        MM(afH, bfH, 4, 2);
        SBAR();

        // P4: Q(mLo,nHi); no reads; stage B-lo(T+2); counted vmcnt certifies tile T+1
        if (T + 2 < NTL) STAGE_B(c, 0, T + 2);
        if (T < NTL - 2) { VMF(6); } else { VMF(0); }
        SBAR();
        MM(afL, bfH, 0, 2);
        SBAR();
    }

    __syncthreads();

    // ---------- fused GroupNorm epilogue ----------
    // acc[mi][n][r]: row = mi*32+wr*16+l4*4+r, col = n*64+wc*16+l15
    // group 0 = cols 0-127 (n=0,1), group 1 = cols 128-255 (n=2,3)
    float* redS  = (float*)pool;            // [256][4wc][2g]
    float* redS2 = (float*)(pool + 8192);
#pragma unroll
    for (int mi = 0; mi < 8; ++mi)
#pragma unroll
        for (int r = 0; r < 4; ++r) {
            float gl  = acc[mi][0][r] + acc[mi][1][r];
            float gh  = acc[mi][2][r] + acc[mi][3][r];
            float gl2 = acc[mi][0][r] * acc[mi][0][r] + acc[mi][1][r] * acc[mi][1][r];
            float gh2 = acc[mi][2][r] * acc[mi][2][r] + acc[mi][3][r] * acc[mi][3][r];
#pragma unroll
            for (int m = 1; m < 16; m <<= 1) {
                gl  += __shfl_xor(gl,  m);
                gh  += __shfl_xor(gh,  m);
                gl2 += __shfl_xor(gl2, m);
                gh2 += __shfl_xor(gh2, m);
            }
            if (l15 == 0) {
                int R = mi * 32 + wr * 16 + l4 * 4 + r;
                redS [R * 8 + wc * 2]     = gl;
                redS [R * 8 + wc * 2 + 1] = gh;
                redS2[R * 8 + wc * 2]     = gl2;
                redS2[R * 8 + wc * 2 + 1] = gh2;
            }
        }
    __syncthreads();

    float bv[4];
#pragma unroll
    for (int ni = 0; ni < 4; ++ni)
        bv[ni] = bias[bcol + ni * 64 + wc * 16 + l15];

    const float inv_gs = 1.0f / 128.0f;
#pragma unroll
    for (int mi = 0; mi < 8; ++mi)
#pragma unroll
        for (int r = 0; r < 4; ++r) {
            int R = mi * 32 + wr * 16 + l4 * 4 + r;
            float S0 = redS [R * 8 + 0] + redS [R * 8 + 2] + redS [R * 8 + 4] + redS [R * 8 + 6];
            float S1 = redS [R * 8 + 1] + redS [R * 8 + 3] + redS [R * 8 + 5] + redS [R * 8 + 7];
            float T0 = redS2[R * 8 + 0] + redS2[R * 8 + 2] + redS2[R * 8 + 4] + redS2[R * 8 + 6];
            float T1 = redS2[R * 8 + 1] + redS2[R * 8 + 3] + redS2[R * 8 + 5] + redS2[R * 8 + 7];
            float mean0 = S0 * inv_gs, mean1 = S1 * inv_gs;
            float inv0 = rsqrtf(T0 * inv_gs - mean0 * mean0 + 1e-6f);
            float inv1 = rsqrtf(T1 * inv_gs - mean1 * mean1 + 1e-6f);
            size_t rowbase = (size_t)(brow + R) * N_DIM + bcol + wc * 16 + l15;
#pragma unroll
            for (int ni = 0; ni < 4; ++ni) {
                float mean = (ni < 2) ? mean0 : mean1;
                float inv  = (ni < 2) ? inv0  : inv1;
                float v = (acc[mi][ni][r] - mean) * inv + bv[ni];
                v = fminf(fmaxf(v, -2.0f), 2.0f);
                out[rowbase + ni * 64] = v;
            }
        }
}

extern "C" void kernel_launch(void* const* d_in, const int* in_sizes, int n_in,
                              void* d_out, int out_size, void* d_ws, size_t ws_size,
                              hipStream_t stream) {
    const float* x = (const float*)d_in[0];
    const float* W = (const float*)d_in[1];
    const float* b = (const float*)d_in[2];
    float* out = (float*)d_out;

    ushort_t* xb = (ushort_t*)d_ws;                       // 64 MB
    ushort_t* wb = xb + (size_t)M_DIM * K_DIM;            // +32 MB

    int n4x = M_DIM * K_DIM / 4;
    cvt_f32_bf16<<<(n4x + 255) / 256, 256, 0, stream>>>(
        (const float4*)x, xb, n4x);
    int n4w = N_DIM * K_DIM / 4;
    cvt_f32_bf16<<<(n4w + 255) / 256, 256, 0, stream>>>(
        (const float4*)W, wb, n4w);

    int grid = (M_DIM / BM) * (N_DIM / BN);               // 512 blocks
    gemm_gn_kernel<<<grid, 512, 0, stream>>>(xb, wb, b, out);
}